// Round 6
// baseline (813.866 us; speedup 1.0000x reference)
//
#include <hip/hip_runtime.h>
#include <hip/hip_bf16.h>
#include <math.h>

typedef __bf16 bf16;
typedef __bf16 bf16x8 __attribute__((ext_vector_type(8)));
typedef __bf16 bf16x4 __attribute__((ext_vector_type(4)));
typedef float f32x4 __attribute__((ext_vector_type(4)));

#define KM 32768   // B*T

__device__ __forceinline__ void gload16(const void* g, void* l) {
  __builtin_amdgcn_global_load_lds((const __attribute__((address_space(1))) void*)g,
                                   (__attribute__((address_space(3))) void*)l, 16, 0, 0);
}

__device__ __forceinline__ float gelu_exact(float x) {
  return 0.5f * x * (1.0f + erff(x * 0.70710678118654752f));
}

// ---------------- W[K][N] fp32 -> Wt[N][K] bf16 ----------------
__global__ void transpose_kernel(const float* __restrict__ W, bf16* __restrict__ Wt,
                                 int K, int N) {
  __shared__ float t[32][33];
  int k0 = blockIdx.x * 32, n0 = blockIdx.y * 32;
  int tx = threadIdx.x & 31, ty = threadIdx.x >> 5;  // 32 x 8
  #pragma unroll
  for (int j = 0; j < 32; j += 8) t[ty + j][tx] = W[(size_t)(k0 + ty + j) * N + n0 + tx];
  __syncthreads();
  #pragma unroll
  for (int j = 0; j < 32; j += 8)
    Wt[(size_t)(n0 + ty + j) * K + k0 + tx] = (bf16)t[tx][ty + j];
}

// ======== 128x128 hybrid MFMA GEMM: A direct global->VGPR, B via swizzled LDS ========
// + T1 XCD-chunked block swizzle. A [M][K] bf16 (ASRC=0) or fused fp32 triple (ASRC=1),
// Bt [N][K] bf16. C = A*B (+bias)(+act)(+res) -> bf16.
template<int ACT, bool RES, int ASRC>
__global__ void gemm_kernel(const bf16* __restrict__ A,
                            const float* __restrict__ Af0, const float* __restrict__ Af1,
                            const float* __restrict__ Af2,
                            const bf16* __restrict__ Bt,
                            const float* __restrict__ bias, const bf16* __restrict__ res,
                            bf16* __restrict__ C, int N, int K, int nbn) {
  __shared__ __align__(16) bf16 lds[128 * 64];   // B tile only (swizzled)
  int nwg = gridDim.x;
  int bid0 = blockIdx.x;
  int bid = (nwg & 7) ? bid0 : ((bid0 & 7) * (nwg >> 3) + (bid0 >> 3));
  int bn = bid % nbn, bm = bid / nbn;
  int tid = threadIdx.x;
  int w = tid >> 6, L = tid & 63;
  int wm = w >> 1, wn = w & 1;
  // B staging: inverse-swizzled global source, linear LDS dest (ERRATA #21; conflicts=0)
  int srow = L >> 3;
  int scol = 8 * ((L & 7) ^ srow);
  const bf16* Bb = Bt + (size_t)(bn * 128) * K;
  f32x4 acc[4][4] = {};
  int nkt = (K + 63) >> 6;
  // per-lane A addressing: global row, k-offset within K-tile
  int arow = bm * 128 + wm * 64 + (L & 15);      // + m*16
  int aoff = (L >> 4) * 8;                        // + kk*32
  for (int kt = 0; kt < nkt; ++kt) {
    int k0 = kt << 6;
    // ---- stage B tile for kt ----
    #pragma unroll
    for (int i = 0; i < 4; ++i) {
      int row = w * 32 + i * 8;
      gload16(Bb + (size_t)(row + srow) * K + k0 + scol, &lds[row * 64]);
    }
    // ---- A fragment loads for kt (global -> regs; drain together with staging) ----
    bf16x8 af[4][2];
    if (ASRC == 0) {
      #pragma unroll
      for (int m = 0; m < 4; ++m)
        #pragma unroll
        for (int kk = 0; kk < 2; ++kk)
          af[m][kk] = *reinterpret_cast<const bf16x8*>(
              A + (size_t)(arow + m * 16) * K + k0 + kk * 32 + aoff);
    } else {
      const float* fsrc; int fstride, fk;
      if (kt < 8)       { fsrc = Af0; fstride = 512; fk = k0; }
      else if (kt < 16) { fsrc = Af1; fstride = 512; fk = k0 - 512; }
      else              { fsrc = Af2; fstride = 64;  fk = 0; }
      #pragma unroll
      for (int m = 0; m < 4; ++m)
        #pragma unroll
        for (int kk = 0; kk < 2; ++kk) {
          const float4* p = reinterpret_cast<const float4*>(
              fsrc + (size_t)(arow + m * 16) * fstride + fk + kk * 32 + aoff);
          float4 v0 = p[0], v1 = p[1];
          bf16x8 t;
          t[0] = (bf16)v0.x; t[1] = (bf16)v0.y; t[2] = (bf16)v0.z; t[3] = (bf16)v0.w;
          t[4] = (bf16)v1.x; t[5] = (bf16)v1.y; t[6] = (bf16)v1.z; t[7] = (bf16)v1.w;
          af[m][kk] = t;
        }
    }
    __syncthreads();   // drains B staging (and A loads) before LDS reads
    #pragma unroll
    for (int kk = 0; kk < 2; ++kk) {
      bf16x8 bfr[4];
      int cb = kk * 64 + ((L >> 4) * 16);
      #pragma unroll
      for (int n = 0; n < 4; ++n) {
        int r = wn * 64 + n * 16 + (L & 15);
        int addr = r * 128 + (cb ^ ((r & 7) << 4));
        bfr[n] = *reinterpret_cast<const bf16x8*>(
            reinterpret_cast<const char*>(&lds[0]) + addr);
      }
      #pragma unroll
      for (int m = 0; m < 4; ++m)
        #pragma unroll
        for (int n = 0; n < 4; ++n)
          acc[m][n] = __builtin_amdgcn_mfma_f32_16x16x32_bf16(af[m][kk], bfr[n], acc[m][n], 0, 0, 0);
    }
    __syncthreads();
  }
  // epilogue: D row = (L>>4)*4 + reg, col = L&15  [m89-verified layout]
  int cn0 = bn * 128 + wn * 64;
  float bv[4];
  #pragma unroll
  for (int n = 0; n < 4; ++n) bv[n] = bias[cn0 + n * 16 + (L & 15)];
  #pragma unroll
  for (int m = 0; m < 4; ++m) {
    int grow0 = bm * 128 + wm * 64 + m * 16 + ((L >> 4) << 2);
    #pragma unroll
    for (int r = 0; r < 4; ++r) {
      size_t ro = (size_t)(grow0 + r) * N;
      #pragma unroll
      for (int n = 0; n < 4; ++n) {
        float v = acc[m][n][r] + bv[n];
        if (ACT == 1) v = gelu_exact(v);
        int col = cn0 + n * 16 + (L & 15);
        if (RES) v += (float)res[ro + col];
        C[ro + col] = (bf16)v;
      }
    }
  }
}

// ---------------- row LayerNorm in-place on bf16 [rows][1024] ----------------
__global__ void ln_inplace_kernel(bf16* __restrict__ X, const float* __restrict__ g,
                                  const float* __restrict__ b) {
  __shared__ float sb[4];
  size_t row = blockIdx.x;
  bf16* xr = X + row * 1024;
  int tid = threadIdx.x;
  bf16x4 xv = *reinterpret_cast<const bf16x4*>(xr + tid * 4);
  float x[4];
  #pragma unroll
  for (int i = 0; i < 4; ++i) x[i] = (float)xv[i];
  float s = x[0] + x[1] + x[2] + x[3];
  #pragma unroll
  for (int off = 32; off > 0; off >>= 1) s += __shfl_xor(s, off);
  if ((tid & 63) == 0) sb[tid >> 6] = s;
  __syncthreads();
  float mu = (sb[0] + sb[1] + sb[2] + sb[3]) * (1.0f / 1024.0f);
  __syncthreads();
  float d[4], sq = 0.f;
  #pragma unroll
  for (int i = 0; i < 4; ++i) { d[i] = x[i] - mu; sq += d[i] * d[i]; }
  #pragma unroll
  for (int off = 32; off > 0; off >>= 1) sq += __shfl_xor(sq, off);
  if ((tid & 63) == 0) sb[tid >> 6] = sq;
  __syncthreads();
  float var = (sb[0] + sb[1] + sb[2] + sb[3]) * (1.0f / 1024.0f);
  float rs = rsqrtf(var + 1e-5f);
  bf16x4 ov;
  #pragma unroll
  for (int i = 0; i < 4; ++i) ov[i] = (bf16)(d[i] * rs * g[tid * 4 + i] + b[tid * 4 + i]);
  *reinterpret_cast<bf16x4*>(xr + tid * 4) = ov;
}

// ---------------- objectness head: sigmoid(o1 . W2 + b2) ----------------
__global__ void obj_kernel(const bf16* __restrict__ o1, const float* __restrict__ W2,
                           const float* __restrict__ b2, float* __restrict__ obj,
                           float* __restrict__ out_obj) {
  __shared__ float w[512];
  int tid = threadIdx.x;
  w[tid] = W2[tid]; w[tid + 256] = W2[tid + 256];
  __syncthreads();
  int wv = tid >> 6, L = tid & 63;
  size_t m = (size_t)blockIdx.x * 4 + wv;
  bf16x8 v = *reinterpret_cast<const bf16x8*>(o1 + m * 512 + L * 8);
  float s = 0.f;
  #pragma unroll
  for (int j = 0; j < 8; ++j) s += (float)v[j] * w[L * 8 + j];
  #pragma unroll
  for (int off = 32; off > 0; off >>= 1) s += __shfl_xor(s, off);
  if (L == 0) {
    float o = 1.0f / (1.0f + expf(-(s + b2[0])));
    obj[m] = o; out_obj[m] = o;
  }
}

// ---------------- attn logits via MFMA: seq[32768x1024] @ tq^T[1024x16] ----------------
__global__ void attn_logits_mfma(const bf16* __restrict__ seq, const float* __restrict__ tq,
                                 const float* __restrict__ obj, float* __restrict__ logits) {
  __shared__ bf16 tqs[16][1032];
  int tid = threadIdx.x;
  for (int i = tid; i < 4096; i += 256) {
    int idx = i * 4;
    int n = idx >> 10, k = idx & 1023;
    float4 v = *reinterpret_cast<const float4*>(tq + idx);
    bf16x4 p; p[0] = (bf16)v.x; p[1] = (bf16)v.y; p[2] = (bf16)v.z; p[3] = (bf16)v.w;
    *reinterpret_cast<bf16x4*>(&tqs[n][k]) = p;
  }
  __syncthreads();
  int w = tid >> 6, L = tid & 63;
  int row0 = blockIdx.x * 128 + w * 32;
  const bf16* A0 = seq + (size_t)(row0 + (L & 15)) * 1024 + ((L >> 4) * 8);
  const bf16* Bq = &tqs[L & 15][(L >> 4) * 8];
  f32x4 acc0 = {}, acc1 = {};
  #pragma unroll 4
  for (int kt = 0; kt < 32; ++kt) {
    int k0 = kt * 32;
    bf16x8 bq = *reinterpret_cast<const bf16x8*>(Bq + k0);
    bf16x8 a0 = *reinterpret_cast<const bf16x8*>(A0 + k0);
    bf16x8 a1 = *reinterpret_cast<const bf16x8*>(A0 + 16 * 1024 + k0);
    acc0 = __builtin_amdgcn_mfma_f32_16x16x32_bf16(a0, bq, acc0, 0, 0, 0);
    acc1 = __builtin_amdgcn_mfma_f32_16x16x32_bf16(a1, bq, acc1, 0, 0, 0);
  }
  int b = row0 >> 12;
  int n = L & 15;
  float* outn = logits + ((size_t)(b * 16) + n) * 4096;
  #pragma unroll
  for (int mf = 0; mf < 2; ++mf) {
    int mrow = row0 + mf * 16 + ((L >> 4) << 2);
    #pragma unroll
    for (int r = 0; r < 4; ++r) {
      int m = mrow + r;
      float v = (mf == 0 ? acc0[r] : acc1[r]) * 0.03125f + 1.5f * obj[m];
      outn[m & 4095] = v;
    }
  }
}

// ---------------- softmax over T=4096 per (b,n) ----------------
__global__ void softmax_kernel(const float* __restrict__ logits, float* __restrict__ attn) {
  __shared__ float sb[4];
  size_t row = blockIdx.x;
  const float* lr = logits + row * 4096;
  float* orow = attn + row * 4096;
  int tid = threadIdx.x;
  float x[16];
  #pragma unroll
  for (int i = 0; i < 4; ++i) {
    float4 v = *reinterpret_cast<const float4*>(lr + tid * 16 + i * 4);
    x[i * 4 + 0] = v.x; x[i * 4 + 1] = v.y; x[i * 4 + 2] = v.z; x[i * 4 + 3] = v.w;
  }
  float mx = -1e30f;
  #pragma unroll
  for (int j = 0; j < 16; ++j) mx = fmaxf(mx, x[j]);
  #pragma unroll
  for (int off = 32; off > 0; off >>= 1) mx = fmaxf(mx, __shfl_xor(mx, off));
  if ((tid & 63) == 0) sb[tid >> 6] = mx;
  __syncthreads();
  mx = fmaxf(fmaxf(sb[0], sb[1]), fmaxf(sb[2], sb[3]));
  __syncthreads();
  float s = 0.f;
  #pragma unroll
  for (int j = 0; j < 16; ++j) { x[j] = expf(x[j] - mx); s += x[j]; }
  #pragma unroll
  for (int off = 32; off > 0; off >>= 1) s += __shfl_xor(s, off);
  if ((tid & 63) == 0) sb[tid >> 6] = s;
  __syncthreads();
  float inv = 1.0f / (sb[0] + sb[1] + sb[2] + sb[3]);
  #pragma unroll
  for (int i = 0; i < 4; ++i) {
    float4 v = make_float4(x[i * 4] * inv, x[i * 4 + 1] * inv, x[i * 4 + 2] * inv, x[i * 4 + 3] * inv);
    *reinterpret_cast<float4*>(orow + tid * 16 + i * 4) = v;
  }
}

// ---------------- token_values: sum_t attn[b,n,t]*seq[b,t,h], T split 4 ways ----------------
__global__ void token_values_kernel(const float* __restrict__ attn, const bf16* __restrict__ seq,
                                    float* __restrict__ tvp) {
  int bid = blockIdx.x;
  int split = bid & 3;
  int hc = (bid >> 2) & 15;
  int b = bid >> 6;
  __shared__ float al[16][256];
  int h = hc * 64 + (threadIdx.x & 63);
  int grp = threadIdx.x >> 6;
  float acc[4] = {0.f, 0.f, 0.f, 0.f};
  for (int c = 0; c < 4; ++c) {
    int t0 = split * 1024 + c * 256;
    __syncthreads();
    for (int i = threadIdx.x; i < 4096; i += 256)
      al[i >> 8][i & 255] = attn[((size_t)b * 16 + (i >> 8)) * 4096 + t0 + (i & 255)];
    __syncthreads();
    for (int tt = 0; tt < 256; ++tt) {
      float s = (float)seq[((size_t)b * 4096 + t0 + tt) * 1024 + h];
      #pragma unroll
      for (int i = 0; i < 4; ++i) acc[i] += al[grp * 4 + i][tt] * s;
    }
  }
  #pragma unroll
  for (int i = 0; i < 4; ++i)
    tvp[(size_t)split * 131072 + ((size_t)b * 16 + grp * 4 + i) * 1024 + h] = acc[i];
}

// ---------------- final LN: LN(tq + sum_parts(tv)) -> fp32 out ----------------
__global__ void final_ln_kernel(const float* __restrict__ tq, const float* __restrict__ tvp,
                                const float* __restrict__ g, const float* __restrict__ bb,
                                float* __restrict__ out0) {
  __shared__ float sb[4];
  int row = blockIdx.x;
  int n = row & 15;
  int tid = threadIdx.x;
  float x[4];
  #pragma unroll
  for (int i = 0; i < 4; ++i) {
    int h = tid * 4 + i;
    float v = tq[n * 1024 + h];
    #pragma unroll
    for (int p = 0; p < 4; ++p) v += tvp[(size_t)p * 131072 + (size_t)row * 1024 + h];
    x[i] = v;
  }
  float s = x[0] + x[1] + x[2] + x[3];
  #pragma unroll
  for (int off = 32; off > 0; off >>= 1) s += __shfl_xor(s, off);
  if ((tid & 63) == 0) sb[tid >> 6] = s;
  __syncthreads();
  float mu = (sb[0] + sb[1] + sb[2] + sb[3]) * (1.0f / 1024.0f);
  __syncthreads();
  float d[4], sq = 0.f;
  #pragma unroll
  for (int i = 0; i < 4; ++i) { d[i] = x[i] - mu; sq += d[i] * d[i]; }
  #pragma unroll
  for (int off = 32; off > 0; off >>= 1) sq += __shfl_xor(sq, off);
  if ((tid & 63) == 0) sb[tid >> 6] = sq;
  __syncthreads();
  float var = (sb[0] + sb[1] + sb[2] + sb[3]) * (1.0f / 1024.0f);
  float rs = rsqrtf(var + 1e-5f);
  #pragma unroll
  for (int i = 0; i < 4; ++i) {
    int h = tid * 4 + i;
    out0[(size_t)row * 1024 + h] = d[i] * rs * g[h] + bb[h];
  }
}

extern "C" void kernel_launch(void* const* d_in, const int* in_sizes, int n_in,
                              void* d_out, int out_size, void* d_ws, size_t ws_size,
                              hipStream_t stream) {
  const float* tr      = (const float*)d_in[0];
  const float* se      = (const float*)d_in[1];
  const float* pr      = (const float*)d_in[2];
  const float* W_in    = (const float*)d_in[3];
  const float* b_in    = (const float*)d_in[4];
  const float* ln_in_g = (const float*)d_in[5];
  const float* ln_in_b = (const float*)d_in[6];
  const float* W_m1    = (const float*)d_in[7];
  const float* b_m1    = (const float*)d_in[8];
  const float* W_m2    = (const float*)d_in[9];
  const float* b_m2    = (const float*)d_in[10];
  const float* W_o1    = (const float*)d_in[11];
  const float* b_o1    = (const float*)d_in[12];
  const float* W_o2    = (const float*)d_in[13];
  const float* b_o2    = (const float*)d_in[14];
  const float* tq      = (const float*)d_in[15];
  const float* ln_out_g= (const float*)d_in[16];
  const float* ln_out_b= (const float*)d_in[17];

  float* out       = (float*)d_out;
  float* out_state = out;                       // [8,16,1024]
  float* out_attn  = out + 131072;              // [8,16,4096]
  float* out_obj   = out + 131072 + 524288;     // [8,4096]

  char* ws = (char*)d_ws;
  size_t off = 0;
  auto alloc = [&](size_t bytes) {
    char* p = ws + off;
    off += (bytes + 255) & ~(size_t)255;
    return p;
  };
  bf16*  t1   = (bf16*)alloc(67108864);   // gelu(h@W_m1+b_m1)
  bf16*  hb   = (bf16*)alloc(67108864);   // h; later reused as o1
  bf16*  o1   = hb;
  bf16*  sq   = (bf16*)alloc(67108864);   // h+mlp -> seq_hidden (LN in place)
  bf16*  WbIn = (bf16*)alloc(2228224);
  bf16*  WbM1 = (bf16*)alloc(2097152);
  bf16*  WbM2 = (bf16*)alloc(2097152);
  bf16*  WbO1 = (bf16*)alloc(1048576);
  float* objw = (float*)alloc(131072 * 4);
  float* logw = (float*)alloc(2097152);
  float* tvp  = (float*)alloc(2097152);

  transpose_kernel<<<dim3(34, 32), 256, 0, stream>>>(W_in, WbIn, 1088, 1024);
  transpose_kernel<<<dim3(32, 32), 256, 0, stream>>>(W_m1, WbM1, 1024, 1024);
  transpose_kernel<<<dim3(32, 32), 256, 0, stream>>>(W_m2, WbM2, 1024, 1024);
  transpose_kernel<<<dim3(32, 16), 256, 0, stream>>>(W_o1, WbO1, 1024, 512);

  // h = fused@W_in + b_in  (A = fp32 triple, fused+converted in-register)
  gemm_kernel<0, false, 1><<<256 * 8, 256, 0, stream>>>(
      nullptr, tr, se, pr, WbIn, b_in, nullptr, hb, 1024, 1088, 8);
  // t1 = gelu(h@W_m1 + b_m1)
  gemm_kernel<1, false, 0><<<256 * 8, 256, 0, stream>>>(
      hb, nullptr, nullptr, nullptr, WbM1, b_m1, nullptr, t1, 1024, 1024, 8);
  // s = h + (t1@W_m2 + b_m2)
  gemm_kernel<0, true, 0><<<256 * 8, 256, 0, stream>>>(
      t1, nullptr, nullptr, nullptr, WbM2, b_m2, hb, sq, 1024, 1024, 8);
  // seq_hidden = LN(s)
  ln_inplace_kernel<<<32768, 256, 0, stream>>>(sq, ln_in_g, ln_in_b);
  // o1 = gelu(seq@W_o1 + b_o1)
  gemm_kernel<1, false, 0><<<256 * 4, 256, 0, stream>>>(
      sq, nullptr, nullptr, nullptr, WbO1, b_o1, nullptr, o1, 512, 1024, 4);
  // objectness
  obj_kernel<<<8192, 256, 0, stream>>>(o1, W_o2, b_o2, objw, out_obj);
  // attn logits (MFMA) + softmax
  attn_logits_mfma<<<256, 256, 0, stream>>>(sq, tq, objw, logw);
  softmax_kernel<<<128, 256, 0, stream>>>(logw, out_attn);
  // token values + final LN
  token_values_kernel<<<512, 256, 0, stream>>>(out_attn, sq, tvp);
  final_ln_kernel<<<128, 256, 0, stream>>>(tq, tvp, ln_out_g, ln_out_b, out_state);
}

// Round 7
// 455.712 us; speedup vs baseline: 1.7859x; 1.7859x over previous
//
#include <hip/hip_runtime.h>
#include <hip/hip_bf16.h>
#include <math.h>

typedef __bf16 bf16;
typedef __bf16 bf16x8 __attribute__((ext_vector_type(8)));
typedef __bf16 bf16x4 __attribute__((ext_vector_type(4)));
typedef float f32x4 __attribute__((ext_vector_type(4)));

#define KM 32768   // B*T

__device__ __forceinline__ void gload16(const void* g, void* l) {
  __builtin_amdgcn_global_load_lds((const __attribute__((address_space(1))) void*)g,
                                   (__attribute__((address_space(3))) void*)l, 16, 0, 0);
}

__device__ __forceinline__ float gelu_exact(float x) {
  return 0.5f * x * (1.0f + erff(x * 0.70710678118654752f));
}

// ---------------- all 4 weight transposes in one dispatch ----------------
// W[K][N] fp32 -> Wt[N][K] bf16
__global__ void transpose_all(const float* __restrict__ W_in, const float* __restrict__ W_m1,
                              const float* __restrict__ W_m2, const float* __restrict__ W_o1,
                              bf16* __restrict__ WbIn, bf16* __restrict__ WbM1,
                              bf16* __restrict__ WbM2, bf16* __restrict__ WbO1) {
  __shared__ float t[32][33];
  int b = blockIdx.x;
  const float* W; bf16* Wt; int K, N, kb, nb;
  if (b < 1088)      { W = W_in; Wt = WbIn; K = 1088; N = 1024; kb = b % 34;  nb = b / 34; }
  else if (b < 2112) { int c = b - 1088; W = W_m1; Wt = WbM1; K = 1024; N = 1024; kb = c & 31; nb = c >> 5; }
  else if (b < 3136) { int c = b - 2112; W = W_m2; Wt = WbM2; K = 1024; N = 1024; kb = c & 31; nb = c >> 5; }
  else               { int c = b - 3136; W = W_o1; Wt = WbO1; K = 1024; N = 512;  kb = c & 31; nb = c >> 5; }
  int k0 = kb * 32, n0 = nb * 32;
  int tx = threadIdx.x & 31, ty = threadIdx.x >> 5;  // 32 x 8
  #pragma unroll
  for (int j = 0; j < 32; j += 8) t[ty + j][tx] = W[(size_t)(k0 + ty + j) * N + n0 + tx];
  __syncthreads();
  #pragma unroll
  for (int j = 0; j < 32; j += 8)
    Wt[(size_t)(n0 + ty + j) * K + k0 + tx] = (bf16)t[tx][ty + j];
}

// ======== 128x128 MFMA GEMM (R5-proven), BK=64, 4 waves, T1 XCD swizzle ========
// ASRC=0: A bf16 [M][K] via global_load_lds.
// ASRC=1: A = concat(tr|se|pr) fp32, reg-staged + converted into the SAME LDS layout.
// OBJ=1: no C write; epilogue computes per-row partial dot with w2 -> objp[bn*2+wn][row].
template<int ACT, bool RES, int ASRC, bool OBJ>
__global__ void gemm_kernel(const bf16* __restrict__ A,
                            const float* __restrict__ Af0, const float* __restrict__ Af1,
                            const float* __restrict__ Af2,
                            const bf16* __restrict__ Bt,
                            const float* __restrict__ bias, const bf16* __restrict__ res,
                            bf16* __restrict__ C, const float* __restrict__ w2,
                            float* __restrict__ objp, int N, int K, int nbn) {
  __shared__ __align__(16) bf16 lds[2][128 * 64];
  int nwg = gridDim.x;
  int bid0 = blockIdx.x;
  int bid = (nwg & 7) ? bid0 : ((bid0 & 7) * (nwg >> 3) + (bid0 >> 3));
  int bn = bid % nbn, bm = bid / nbn;
  int tid = threadIdx.x;
  int w = tid >> 6, L = tid & 63;
  int wm = w >> 1, wn = w & 1;
  // staging mapping: LDS row rd = row_base + (L>>3); slot s = L&7 holds source cols 8*(s^(rd&7))
  int srow = L >> 3;
  int scol = 8 * ((L & 7) ^ srow);
  const bf16* Ab = (ASRC == 0) ? A + (size_t)(bm * 128) * K : nullptr;
  const bf16* Bb = Bt + (size_t)(bn * 128) * K;
  f32x4 acc[4][4] = {};
  int nkt = (K + 63) >> 6;
  for (int kt = 0; kt < nkt; ++kt) {
    int k0 = kt << 6;
    // ---- stage B (async gload16) ----
    #pragma unroll
    for (int i = 0; i < 4; ++i) {
      int row = w * 32 + i * 8;
      gload16(Bb + (size_t)(row + srow) * K + k0 + scol, &lds[1][row * 64]);
    }
    // ---- stage A ----
    if (ASRC == 0) {
      #pragma unroll
      for (int i = 0; i < 4; ++i) {
        int row = w * 32 + i * 8;
        gload16(Ab + (size_t)(row + srow) * K + k0 + scol, &lds[0][row * 64]);
      }
    } else {
      const float* fsrc; int fstr, fk;
      if (kt < 8)       { fsrc = Af0; fstr = 512; fk = k0; }
      else if (kt < 16) { fsrc = Af1; fstr = 512; fk = k0 - 512; }
      else              { fsrc = Af2; fstr = 64;  fk = 0; }
      #pragma unroll
      for (int i = 0; i < 4; ++i) {
        int row = w * 32 + i * 8;
        const float* src = fsrc + (size_t)(bm * 128 + row + srow) * fstr + fk + scol;
        float4 v0 = *reinterpret_cast<const float4*>(src);
        float4 v1 = *reinterpret_cast<const float4*>(src + 4);
        bf16x8 tv;
        tv[0] = (bf16)v0.x; tv[1] = (bf16)v0.y; tv[2] = (bf16)v0.z; tv[3] = (bf16)v0.w;
        tv[4] = (bf16)v1.x; tv[5] = (bf16)v1.y; tv[6] = (bf16)v1.z; tv[7] = (bf16)v1.w;
        *reinterpret_cast<bf16x8*>(&lds[0][row * 64 + L * 8]) = tv;
      }
    }
    __syncthreads();   // drains vmcnt + lgkm before LDS reads
    #pragma unroll
    for (int kk = 0; kk < 2; ++kk) {
      bf16x8 af[4], bfr[4];
      int cb = kk * 64 + ((L >> 4) * 16);
      #pragma unroll
      for (int m = 0; m < 4; ++m) {
        int r = wm * 64 + m * 16 + (L & 15);
        int addr = r * 128 + (cb ^ ((r & 7) << 4));
        af[m] = *reinterpret_cast<const bf16x8*>(
            reinterpret_cast<const char*>(&lds[0][0]) + addr);
      }
      #pragma unroll
      for (int n = 0; n < 4; ++n) {
        int r = wn * 64 + n * 16 + (L & 15);
        int addr = r * 128 + (cb ^ ((r & 7) << 4));
        bfr[n] = *reinterpret_cast<const bf16x8*>(
            reinterpret_cast<const char*>(&lds[1][0]) + addr);
      }
      #pragma unroll
      for (int m = 0; m < 4; ++m)
        #pragma unroll
        for (int n = 0; n < 4; ++n)
          acc[m][n] = __builtin_amdgcn_mfma_f32_16x16x32_bf16(af[m], bfr[n], acc[m][n], 0, 0, 0);
    }
    __syncthreads();
  }
  // ---- epilogue: D row = (L>>4)*4 + reg, col = L&15 ----
  int cn0 = bn * 128 + wn * 64;
  float bv[4];
  #pragma unroll
  for (int n = 0; n < 4; ++n) bv[n] = bias[cn0 + n * 16 + (L & 15)];
  if (OBJ) {
    float w2v[4];
    #pragma unroll
    for (int n = 0; n < 4; ++n) w2v[n] = w2[cn0 + n * 16 + (L & 15)];
    float* op = objp + (size_t)(bn * 2 + wn) * KM;
    #pragma unroll
    for (int m = 0; m < 4; ++m) {
      int grow0 = bm * 128 + wm * 64 + m * 16 + ((L >> 4) << 2);
      #pragma unroll
      for (int r = 0; r < 4; ++r) {
        float s = 0.f;
        #pragma unroll
        for (int n = 0; n < 4; ++n) {
          float v = gelu_exact(acc[m][n][r] + bv[n]);
          s += v * w2v[n];
        }
        s += __shfl_xor(s, 1); s += __shfl_xor(s, 2);
        s += __shfl_xor(s, 4); s += __shfl_xor(s, 8);
        if ((L & 15) == 0) op[grow0 + r] = s;
      }
    }
  } else {
    #pragma unroll
    for (int m = 0; m < 4; ++m) {
      int grow0 = bm * 128 + wm * 64 + m * 16 + ((L >> 4) << 2);
      #pragma unroll
      for (int r = 0; r < 4; ++r) {
        size_t ro = (size_t)(grow0 + r) * N;
        #pragma unroll
        for (int n = 0; n < 4; ++n) {
          float v = acc[m][n][r] + bv[n];
          if (ACT == 1) v = gelu_exact(v);
          int col = cn0 + n * 16 + (L & 15);
          if (RES) v += (float)res[ro + col];
          C[ro + col] = (bf16)v;
        }
      }
    }
  }
}

// ---------------- row LayerNorm in-place on bf16 [rows][1024] ----------------
__global__ void ln_inplace_kernel(bf16* __restrict__ X, const float* __restrict__ g,
                                  const float* __restrict__ b) {
  __shared__ float sb[4];
  size_t row = blockIdx.x;
  bf16* xr = X + row * 1024;
  int tid = threadIdx.x;
  bf16x4 xv = *reinterpret_cast<const bf16x4*>(xr + tid * 4);
  float x[4];
  #pragma unroll
  for (int i = 0; i < 4; ++i) x[i] = (float)xv[i];
  float s = x[0] + x[1] + x[2] + x[3];
  #pragma unroll
  for (int off = 32; off > 0; off >>= 1) s += __shfl_xor(s, off);
  if ((tid & 63) == 0) sb[tid >> 6] = s;
  __syncthreads();
  float mu = (sb[0] + sb[1] + sb[2] + sb[3]) * (1.0f / 1024.0f);
  __syncthreads();
  float d[4], sq = 0.f;
  #pragma unroll
  for (int i = 0; i < 4; ++i) { d[i] = x[i] - mu; sq += d[i] * d[i]; }
  #pragma unroll
  for (int off = 32; off > 0; off >>= 1) sq += __shfl_xor(sq, off);
  if ((tid & 63) == 0) sb[tid >> 6] = sq;
  __syncthreads();
  float var = (sb[0] + sb[1] + sb[2] + sb[3]) * (1.0f / 1024.0f);
  float rs = rsqrtf(var + 1e-5f);
  bf16x4 ov;
  #pragma unroll
  for (int i = 0; i < 4; ++i) ov[i] = (bf16)(d[i] * rs * g[tid * 4 + i] + b[tid * 4 + i]);
  *reinterpret_cast<bf16x4*>(xr + tid * 4) = ov;
}

// ---------------- attn logits via MFMA: seq[32768x1024] @ tq^T[1024x16] ----------------
// logits = dot*scale + 1.5*sigmoid(sum_p objp[p][m] + b2); also writes out_obj.
__global__ void attn_logits_mfma(const bf16* __restrict__ seq, const float* __restrict__ tq,
                                 const float* __restrict__ objp, const float* __restrict__ b2,
                                 float* __restrict__ logits, float* __restrict__ out_obj) {
  __shared__ bf16 tqs[16][1032];
  int tid = threadIdx.x;
  for (int i = tid; i < 4096; i += 256) {
    int idx = i * 4;
    int n = idx >> 10, k = idx & 1023;
    float4 v = *reinterpret_cast<const float4*>(tq + idx);
    bf16x4 p; p[0] = (bf16)v.x; p[1] = (bf16)v.y; p[2] = (bf16)v.z; p[3] = (bf16)v.w;
    *reinterpret_cast<bf16x4*>(&tqs[n][k]) = p;
  }
  __syncthreads();
  int w = tid >> 6, L = tid & 63;
  int row0 = blockIdx.x * 128 + w * 32;
  const bf16* A0 = seq + (size_t)(row0 + (L & 15)) * 1024 + ((L >> 4) * 8);
  const bf16* Bq = &tqs[L & 15][(L >> 4) * 8];
  f32x4 acc0 = {}, acc1 = {};
  #pragma unroll 4
  for (int kt = 0; kt < 32; ++kt) {
    int k0 = kt * 32;
    bf16x8 bq = *reinterpret_cast<const bf16x8*>(Bq + k0);
    bf16x8 a0 = *reinterpret_cast<const bf16x8*>(A0 + k0);
    bf16x8 a1 = *reinterpret_cast<const bf16x8*>(A0 + 16 * 1024 + k0);
    acc0 = __builtin_amdgcn_mfma_f32_16x16x32_bf16(a0, bq, acc0, 0, 0, 0);
    acc1 = __builtin_amdgcn_mfma_f32_16x16x32_bf16(a1, bq, acc1, 0, 0, 0);
  }
  float b2v = b2[0];
  int b = row0 >> 12;
  int n = L & 15;
  float* outn = logits + ((size_t)(b * 16) + n) * 4096;
  #pragma unroll
  for (int mf = 0; mf < 2; ++mf) {
    int mrow = row0 + mf * 16 + ((L >> 4) << 2);
    // sum the 8 deterministic partials -> obj logit -> sigmoid
    float os0 = 0.f, os1 = 0.f, os2 = 0.f, os3 = 0.f;
    #pragma unroll
    for (int p = 0; p < 8; ++p) {
      float4 t = *reinterpret_cast<const float4*>(objp + (size_t)p * KM + mrow);
      os0 += t.x; os1 += t.y; os2 += t.z; os3 += t.w;
    }
    float ob[4];
    ob[0] = 1.0f / (1.0f + expf(-(os0 + b2v)));
    ob[1] = 1.0f / (1.0f + expf(-(os1 + b2v)));
    ob[2] = 1.0f / (1.0f + expf(-(os2 + b2v)));
    ob[3] = 1.0f / (1.0f + expf(-(os3 + b2v)));
    #pragma unroll
    for (int r = 0; r < 4; ++r) {
      int m = mrow + r;
      float v = (mf == 0 ? acc0[r] : acc1[r]) * 0.03125f + 1.5f * ob[r];
      outn[m & 4095] = v;
    }
    if (n == 0) {
      float4 o4 = make_float4(ob[0], ob[1], ob[2], ob[3]);
      *reinterpret_cast<float4*>(out_obj + mrow) = o4;
    }
  }
}

// ---------------- softmax over T=4096 per (b,n) ----------------
__global__ void softmax_kernel(const float* __restrict__ logits, float* __restrict__ attn) {
  __shared__ float sb[4];
  size_t row = blockIdx.x;
  const float* lr = logits + row * 4096;
  float* orow = attn + row * 4096;
  int tid = threadIdx.x;
  float x[16];
  #pragma unroll
  for (int i = 0; i < 4; ++i) {
    float4 v = *reinterpret_cast<const float4*>(lr + tid * 16 + i * 4);
    x[i * 4 + 0] = v.x; x[i * 4 + 1] = v.y; x[i * 4 + 2] = v.z; x[i * 4 + 3] = v.w;
  }
  float mx = -1e30f;
  #pragma unroll
  for (int j = 0; j < 16; ++j) mx = fmaxf(mx, x[j]);
  #pragma unroll
  for (int off = 32; off > 0; off >>= 1) mx = fmaxf(mx, __shfl_xor(mx, off));
  if ((tid & 63) == 0) sb[tid >> 6] = mx;
  __syncthreads();
  mx = fmaxf(fmaxf(sb[0], sb[1]), fmaxf(sb[2], sb[3]));
  __syncthreads();
  float s = 0.f;
  #pragma unroll
  for (int j = 0; j < 16; ++j) { x[j] = expf(x[j] - mx); s += x[j]; }
  #pragma unroll
  for (int off = 32; off > 0; off >>= 1) s += __shfl_xor(s, off);
  if ((tid & 63) == 0) sb[tid >> 6] = s;
  __syncthreads();
  float inv = 1.0f / (sb[0] + sb[1] + sb[2] + sb[3]);
  #pragma unroll
  for (int i = 0; i < 4; ++i) {
    float4 v = make_float4(x[i * 4] * inv, x[i * 4 + 1] * inv, x[i * 4 + 2] * inv, x[i * 4 + 3] * inv);
    *reinterpret_cast<float4*>(orow + tid * 16 + i * 4) = v;
  }
}

// ---------------- token_values: sum_t attn[b,n,t]*seq[b,t,h], T split 4 ways ----------------
__global__ void token_values_kernel(const float* __restrict__ attn, const bf16* __restrict__ seq,
                                    float* __restrict__ tvp) {
  int bid = blockIdx.x;
  int split = bid & 3;
  int hc = (bid >> 2) & 15;
  int b = bid >> 6;
  __shared__ float al[16][256];
  int h = hc * 64 + (threadIdx.x & 63);
  int grp = threadIdx.x >> 6;
  float acc[4] = {0.f, 0.f, 0.f, 0.f};
  for (int c = 0; c < 4; ++c) {
    int t0 = split * 1024 + c * 256;
    __syncthreads();
    for (int i = threadIdx.x; i < 4096; i += 256)
      al[i >> 8][i & 255] = attn[((size_t)b * 16 + (i >> 8)) * 4096 + t0 + (i & 255)];
    __syncthreads();
    for (int tt = 0; tt < 256; ++tt) {
      float s = (float)seq[((size_t)b * 4096 + t0 + tt) * 1024 + h];
      #pragma unroll
      for (int i = 0; i < 4; ++i) acc[i] += al[grp * 4 + i][tt] * s;
    }
  }
  #pragma unroll
  for (int i = 0; i < 4; ++i)
    tvp[(size_t)split * 131072 + ((size_t)b * 16 + grp * 4 + i) * 1024 + h] = acc[i];
}

// ---------------- final LN: LN(tq + sum_parts(tv)) -> fp32 out ----------------
__global__ void final_ln_kernel(const float* __restrict__ tq, const float* __restrict__ tvp,
                                const float* __restrict__ g, const float* __restrict__ bb,
                                float* __restrict__ out0) {
  __shared__ float sb[4];
  int row = blockIdx.x;
  int n = row & 15;
  int tid = threadIdx.x;
  float x[4];
  #pragma unroll
  for (int i = 0; i < 4; ++i) {
    int h = tid * 4 + i;
    float v = tq[n * 1024 + h];
    #pragma unroll
    for (int p = 0; p < 4; ++p) v += tvp[(size_t)p * 131072 + (size_t)row * 1024 + h];
    x[i] = v;
  }
  float s = x[0] + x[1] + x[2] + x[3];
  #pragma unroll
  for (int off = 32; off > 0; off >>= 1) s += __shfl_xor(s, off);
  if ((tid & 63) == 0) sb[tid >> 6] = s;
  __syncthreads();
  float mu = (sb[0] + sb[1] + sb[2] + sb[3]) * (1.0f / 1024.0f);
  __syncthreads();
  float d[4], sq = 0.f;
  #pragma unroll
  for (int i = 0; i < 4; ++i) { d[i] = x[i] - mu; sq += d[i] * d[i]; }
  #pragma unroll
  for (int off = 32; off > 0; off >>= 1) sq += __shfl_xor(sq, off);
  if ((tid & 63) == 0) sb[tid >> 6] = sq;
  __syncthreads();
  float var = (sb[0] + sb[1] + sb[2] + sb[3]) * (1.0f / 1024.0f);
  float rs = rsqrtf(var + 1e-5f);
  #pragma unroll
  for (int i = 0; i < 4; ++i) {
    int h = tid * 4 + i;
    out0[(size_t)row * 1024 + h] = d[i] * rs * g[h] + bb[h];
  }
}

extern "C" void kernel_launch(void* const* d_in, const int* in_sizes, int n_in,
                              void* d_out, int out_size, void* d_ws, size_t ws_size,
                              hipStream_t stream) {
  const float* tr      = (const float*)d_in[0];
  const float* se      = (const float*)d_in[1];
  const float* pr      = (const float*)d_in[2];
  const float* W_in    = (const float*)d_in[3];
  const float* b_in    = (const float*)d_in[4];
  const float* ln_in_g = (const float*)d_in[5];
  const float* ln_in_b = (const float*)d_in[6];
  const float* W_m1    = (const float*)d_in[7];
  const float* b_m1    = (const float*)d_in[8];
  const float* W_m2    = (const float*)d_in[9];
  const float* b_m2    = (const float*)d_in[10];
  const float* W_o1    = (const float*)d_in[11];
  const float* b_o1    = (const float*)d_in[12];
  const float* W_o2    = (const float*)d_in[13];
  const float* b_o2    = (const float*)d_in[14];
  const float* tq      = (const float*)d_in[15];
  const float* ln_out_g= (const float*)d_in[16];
  const float* ln_out_b= (const float*)d_in[17];

  float* out       = (float*)d_out;
  float* out_state = out;                       // [8,16,1024]
  float* out_attn  = out + 131072;              // [8,16,4096]
  float* out_obj   = out + 131072 + 524288;     // [8,4096]

  char* ws = (char*)d_ws;
  size_t off = 0;
  auto alloc = [&](size_t bytes) {
    char* p = ws + off;
    off += (bytes + 255) & ~(size_t)255;
    return p;
  };
  bf16*  t1   = (bf16*)alloc(67108864);   // gelu(h@W_m1+b_m1)
  bf16*  hb   = (bf16*)alloc(67108864);   // h
  bf16*  sq   = (bf16*)alloc(67108864);   // h+mlp -> seq_hidden (LN in place)
  bf16*  WbIn = (bf16*)alloc(2228224);
  bf16*  WbM1 = (bf16*)alloc(2097152);
  bf16*  WbM2 = (bf16*)alloc(2097152);
  bf16*  WbO1 = (bf16*)alloc(1048576);
  float* objp = (float*)alloc(8 * KM * 4);  // 8 deterministic partials per row
  float* logw = (float*)alloc(2097152);
  float* tvp  = (float*)alloc(2097152);

  transpose_all<<<3648, 256, 0, stream>>>(W_in, W_m1, W_m2, W_o1, WbIn, WbM1, WbM2, WbO1);

  // h = fused(tr|se|pr)@W_in + b_in   (A reg-staged from fp32, fused in staging)
  gemm_kernel<0, false, 1, false><<<2048, 256, 0, stream>>>(
      nullptr, tr, se, pr, WbIn, b_in, nullptr, hb, nullptr, nullptr, 1024, 1088, 8);
  // t1 = gelu(h@W_m1 + b_m1)
  gemm_kernel<1, false, 0, false><<<2048, 256, 0, stream>>>(
      hb, nullptr, nullptr, nullptr, WbM1, b_m1, nullptr, t1, nullptr, nullptr, 1024, 1024, 8);
  // s = h + (t1@W_m2 + b_m2)
  gemm_kernel<0, true, 0, false><<<2048, 256, 0, stream>>>(
      t1, nullptr, nullptr, nullptr, WbM2, b_m2, hb, sq, nullptr, nullptr, 1024, 1024, 8);
  // seq_hidden = LN(s)
  ln_inplace_kernel<<<32768, 256, 0, stream>>>(sq, ln_in_g, ln_in_b);
  // objectness partials: gelu(seq@W_o1+b_o1) . W_o2  (no o1 materialization)
  gemm_kernel<1, false, 0, true><<<1024, 256, 0, stream>>>(
      sq, nullptr, nullptr, nullptr, WbO1, b_o1, nullptr, nullptr, W_o2, objp, 512, 1024, 4);
  // attn logits (MFMA) + sigmoid(obj) + out_obj
  attn_logits_mfma<<<256, 256, 0, stream>>>(sq, tq, objp, b_o2, logw, out_obj);
  softmax_kernel<<<128, 256, 0, stream>>>(logw, out_attn);
  // token values + final LN
  token_values_kernel<<<512, 256, 0, stream>>>(out_attn, sq, tvp);
  final_ln_kernel<<<128, 256, 0, stream>>>(tq, tvp, ln_out_g, ln_out_b, out_state);
}